// Round 1
// baseline (328.808 us; speedup 1.0000x reference)
//
#include <hip/hip_runtime.h>
#include <math.h>

// Problem constants (fixed by the reference)
constexpr int B     = 8;
constexpr int N_PER = 2048;
constexpr int C     = 256;
constexpr int KG    = 16;
constexpr int KTOP  = 512;
constexpr int KNN   = 32;
constexpr int N     = B * N_PER;   // 16384
constexpr float EPS = 1e-5f;

// ---------------------------------------------------------------------------
// K1: T = x @ theta_w.T ;  R = x + x @ phi_w.T + (theta_b + phi_b) - T
// 64x64 output tile per block, BK=16, fp32 VALU outer-product GEMM.
// grid (N/64, C/64), block 256.
// ---------------------------------------------------------------------------
__global__ __launch_bounds__(256) void k1_dual_gemm(
    const float* __restrict__ x, const float* __restrict__ thw,
    const float* __restrict__ phw, const float* __restrict__ thb,
    const float* __restrict__ phb, float* __restrict__ T, float* __restrict__ R)
{
    constexpr int BK = 16, ST = 68;   // ST: padded LDS row stride (16B-aligned rows, conflict-light)
    __shared__ float Xs[BK * ST];
    __shared__ float Wt[BK * ST];
    __shared__ float Wp[BK * ST];
    const int tid  = threadIdx.x;
    const int row0 = blockIdx.x * 64;
    const int n0   = blockIdx.y * 64;
    const int tx = tid & 15, ty = tid >> 4;
    const int lm = tid >> 2, lq = (tid & 3) << 2;

    float aT[4][4] = {{0.f}}, aQ[4][4] = {{0.f}};

    for (int k0 = 0; k0 < C; k0 += BK) {
        float4 fx = *(const float4*)(x   + (size_t)(row0 + lm) * C + k0 + lq);
        float4 ft = *(const float4*)(thw + (size_t)(n0   + lm) * C + k0 + lq);
        float4 fp = *(const float4*)(phw + (size_t)(n0   + lm) * C + k0 + lq);
        __syncthreads();
        Xs[(lq + 0) * ST + lm] = fx.x;  Xs[(lq + 1) * ST + lm] = fx.y;
        Xs[(lq + 2) * ST + lm] = fx.z;  Xs[(lq + 3) * ST + lm] = fx.w;
        Wt[(lq + 0) * ST + lm] = ft.x;  Wt[(lq + 1) * ST + lm] = ft.y;
        Wt[(lq + 2) * ST + lm] = ft.z;  Wt[(lq + 3) * ST + lm] = ft.w;
        Wp[(lq + 0) * ST + lm] = fp.x;  Wp[(lq + 1) * ST + lm] = fp.y;
        Wp[(lq + 2) * ST + lm] = fp.z;  Wp[(lq + 3) * ST + lm] = fp.w;
        __syncthreads();
#pragma unroll
        for (int k = 0; k < BK; ++k) {
            float4 a4 = *(const float4*)&Xs[k * ST + (ty << 2)];
            float4 t4 = *(const float4*)&Wt[k * ST + (tx << 2)];
            float4 p4 = *(const float4*)&Wp[k * ST + (tx << 2)];
            float av[4] = {a4.x, a4.y, a4.z, a4.w};
            float tv[4] = {t4.x, t4.y, t4.z, t4.w};
            float pv[4] = {p4.x, p4.y, p4.z, p4.w};
#pragma unroll
            for (int i2 = 0; i2 < 4; ++i2)
#pragma unroll
                for (int j2 = 0; j2 < 4; ++j2) {
                    aT[i2][j2] += av[i2] * tv[j2];
                    aQ[i2][j2] += av[i2] * pv[j2];
                }
        }
    }
#pragma unroll
    for (int i2 = 0; i2 < 4; ++i2) {
        const int gm = row0 + (ty << 2) + i2;
#pragma unroll
        for (int j2 = 0; j2 < 4; ++j2) {
            const int gn = n0 + (tx << 2) + j2;
            const size_t off = (size_t)gm * C + gn;
            const float tval = aT[i2][j2];
            T[off] = tval;
            R[off] = x[off] + aQ[i2][j2] + thb[gn] + phb[gn] - tval;
        }
    }
}

// ---------------------------------------------------------------------------
// K2a: x1[i] = max_{k<16} T[src[i*16+k]] + R[i]   (R overwritten in place)
// grid N, block 256 (one channel per thread).
// ---------------------------------------------------------------------------
__global__ __launch_bounds__(256) void k2a_gather_max(
    const int* __restrict__ esrc, const float* __restrict__ T, float* x1r)
{
    const int i = blockIdx.x;
    const int c = threadIdx.x;
    __shared__ int s[KG];
    if (c < KG) s[c] = esrc[i * KG + c];
    __syncthreads();
    float m = -INFINITY;
#pragma unroll
    for (int k = 0; k < KG; ++k) m = fmaxf(m, T[(size_t)s[k] * C + c]);
    const size_t off = (size_t)i * C + c;
    x1r[off] = m + x1r[off];
}

// ---------------------------------------------------------------------------
// K2b: t1 = BN1(ReLU(x1 @ w1.T + b1))   [N x 64]
// Same tile structure as K1, single weight. grid (N/64), block 256.
// ---------------------------------------------------------------------------
__global__ __launch_bounds__(256) void k2b_layer1(
    const float* __restrict__ x1, const float* __restrict__ w1,
    const float* __restrict__ b1, const float* __restrict__ g1,
    const float* __restrict__ be1, const float* __restrict__ m1,
    const float* __restrict__ v1, float* __restrict__ t1)
{
    constexpr int BK = 16, ST = 68;
    __shared__ float Xs[BK * ST];
    __shared__ float Ws[BK * ST];
    const int tid  = threadIdx.x;
    const int row0 = blockIdx.x * 64;
    const int tx = tid & 15, ty = tid >> 4;
    const int lm = tid >> 2, lq = (tid & 3) << 2;

    float acc[4][4] = {{0.f}};
    for (int k0 = 0; k0 < C; k0 += BK) {
        float4 fx = *(const float4*)(x1 + (size_t)(row0 + lm) * C + k0 + lq);
        float4 fw = *(const float4*)(w1 + (size_t)lm * C + k0 + lq);
        __syncthreads();
        Xs[(lq + 0) * ST + lm] = fx.x;  Xs[(lq + 1) * ST + lm] = fx.y;
        Xs[(lq + 2) * ST + lm] = fx.z;  Xs[(lq + 3) * ST + lm] = fx.w;
        Ws[(lq + 0) * ST + lm] = fw.x;  Ws[(lq + 1) * ST + lm] = fw.y;
        Ws[(lq + 2) * ST + lm] = fw.z;  Ws[(lq + 3) * ST + lm] = fw.w;
        __syncthreads();
#pragma unroll
        for (int k = 0; k < BK; ++k) {
            float4 a4 = *(const float4*)&Xs[k * ST + (ty << 2)];
            float4 w4 = *(const float4*)&Ws[k * ST + (tx << 2)];
            float av[4] = {a4.x, a4.y, a4.z, a4.w};
            float wv[4] = {w4.x, w4.y, w4.z, w4.w};
#pragma unroll
            for (int i2 = 0; i2 < 4; ++i2)
#pragma unroll
                for (int j2 = 0; j2 < 4; ++j2) acc[i2][j2] += av[i2] * wv[j2];
        }
    }
#pragma unroll
    for (int i2 = 0; i2 < 4; ++i2) {
        const int gm = row0 + (ty << 2) + i2;
#pragma unroll
        for (int j2 = 0; j2 < 4; ++j2) {
            const int gn = (tx << 2) + j2;           // 0..63
            float y = acc[i2][j2] + b1[gn];
            y = fmaxf(y, 0.f);
            const float inv = 1.0f / sqrtf(v1[gn] + EPS);
            y = (y - m1[gn]) * inv * g1[gn] + be1[gn];
            t1[(size_t)gm * 64 + gn] = y;
        }
    }
}

// ---------------------------------------------------------------------------
// K2c: layers 2-3 -> score.  8 nodes per block, block 256.
// ---------------------------------------------------------------------------
__global__ __launch_bounds__(256) void k2c_score(
    const float* __restrict__ t1,
    const float* __restrict__ w2, const float* __restrict__ b2,
    const float* __restrict__ g2, const float* __restrict__ be2,
    const float* __restrict__ m2, const float* __restrict__ v2,
    const float* __restrict__ w3, const float* __restrict__ b3,
    float* __restrict__ score_ws, float* __restrict__ out_score)
{
    __shared__ float w2s[32 * 65];
    __shared__ float t1s[8 * 65];
    __shared__ float zs[8 * 33];
    __shared__ float w3s[32];
    const int t = threadIdx.x;
    const int node0 = blockIdx.x * 8;

    for (int idx = t; idx < 2048; idx += 256) {
        const int oo = idx >> 6, jj = idx & 63;
        w2s[oo * 65 + jj] = w2[idx];
    }
    if (t < 32) w3s[t] = w3[t];
    for (int idx = t; idx < 512; idx += 256) {
        const int nn = idx >> 6, jj = idx & 63;
        t1s[nn * 65 + jj] = t1[(size_t)(node0 + nn) * 64 + jj];
    }
    __syncthreads();

    const int nl = t >> 5, o = t & 31;
    float z = 0.f;
#pragma unroll
    for (int j = 0; j < 64; ++j) z += t1s[nl * 65 + j] * w2s[o * 65 + j];
    z += b2[o];
    z = fmaxf(z, 0.f);
    const float inv = 1.0f / sqrtf(v2[o] + EPS);
    z = (z - m2[o]) * inv * g2[o] + be2[o];
    zs[nl * 33 + o] = z;
    __syncthreads();

    if (t < 8) {
        float s = 0.f;
#pragma unroll
        for (int j = 0; j < 32; ++j) s += zs[t * 33 + j] * w3s[j];
        s += b3[0];
        const int node = node0 + t;
        score_ws[node]  = s;
        out_score[node] = s;
    }
}

// ---------------------------------------------------------------------------
// K3: per-batch top-512 of 2048, descending, ties -> lower index first.
// Bitonic sort of packed keys (desc-mapped score bits << 32 | idx), ascending.
// grid B, block 256.
// ---------------------------------------------------------------------------
__global__ __launch_bounds__(256) void k3_topk(
    const float* __restrict__ score, float* __restrict__ out_topk,
    int* __restrict__ perm)
{
    __shared__ unsigned long long keys[N_PER];
    const int b = blockIdx.x;
    const int t = threadIdx.x;
    for (int i = t; i < N_PER; i += 256) {
        const float v = score[b * N_PER + i];
        unsigned u = __float_as_uint(v);
        const unsigned ua = (u & 0x80000000u) ? ~u : (u | 0x80000000u); // ascending-monotone
        const unsigned ud = ~ua;                                        // descending-monotone
        keys[i] = ((unsigned long long)ud << 32) | (unsigned)i;
    }
    __syncthreads();
    for (int k = 2; k <= N_PER; k <<= 1) {
        for (int j = k >> 1; j > 0; j >>= 1) {
            for (int i = t; i < N_PER; i += 256) {
                const int ixj = i ^ j;
                if (ixj > i) {
                    const unsigned long long a = keys[i], c = keys[ixj];
                    const bool up = ((i & k) == 0);
                    if ((a > c) == up) { keys[i] = c; keys[ixj] = a; }
                }
            }
            __syncthreads();
        }
    }
    for (int r = t; r < KTOP; r += 256) {
        const int idx = (int)(keys[r] & 0xffffffffu);
        out_topk[b * KTOP + r] = score[b * N_PER + idx];
        perm[b * KTOP + r] = b * N_PER + idx;
    }
}

// ---------------------------------------------------------------------------
// K4: gather x_new = x1[perm], x_copy = x_origin[perm], xyz_sel = xyz[perm].
// grid B*KTOP, block 256 (one channel per thread).
// ---------------------------------------------------------------------------
__global__ __launch_bounds__(256) void k4_gather(
    const int* __restrict__ perm, const float* __restrict__ x1,
    const float* __restrict__ xorig, const float* __restrict__ xyz,
    float* __restrict__ out_xnew, float* __restrict__ out_xcopy,
    float* __restrict__ xyz_sel)
{
    const int row = blockIdx.x;
    const int t = threadIdx.x;
    const int g = perm[row];
    out_xnew [(size_t)row * C + t] = x1   [(size_t)g * C + t];
    out_xcopy[(size_t)row * C + t] = xorig[(size_t)g * C + t];
    if (t < 3) xyz_sel[row * 3 + t] = xyz[g * 3 + t];
}

// ---------------------------------------------------------------------------
// K5: per selected point, 32-NN among the 512 selected points of its batch.
// d2 computed with _rn intrinsics in numpy's association -> bit-exact order.
// Ascending (d2, idx) via packed bitonic sort. grid B*KTOP, block 256.
// ---------------------------------------------------------------------------
__global__ __launch_bounds__(256) void k5_knn(
    const float* __restrict__ xyz_sel, float* __restrict__ out_knn)
{
    __shared__ float px[KTOP], py[KTOP], pz[KTOP];
    __shared__ unsigned long long keys[KTOP];
    const int b = blockIdx.x >> 9;
    const int i = blockIdx.x & 511;
    const int t = threadIdx.x;
    for (int idx = t; idx < KTOP; idx += 256) {
        const float* p = xyz_sel + ((size_t)b * KTOP + idx) * 3;
        px[idx] = p[0]; py[idx] = p[1]; pz[idx] = p[2];
    }
    __syncthreads();
    const float qx = px[i], qy = py[i], qz = pz[i];
    for (int idx = t; idx < KTOP; idx += 256) {
        const float dx = __fsub_rn(qx, px[idx]);
        const float dy = __fsub_rn(qy, py[idx]);
        const float dz = __fsub_rn(qz, pz[idx]);
        const float d2 = __fadd_rn(__fadd_rn(__fmul_rn(dx, dx), __fmul_rn(dy, dy)),
                                   __fmul_rn(dz, dz));
        keys[idx] = ((unsigned long long)__float_as_uint(d2) << 32) | (unsigned)idx;
    }
    __syncthreads();
    for (int k = 2; k <= KTOP; k <<= 1) {
        for (int j = k >> 1; j > 0; j >>= 1) {
            for (int ii = t; ii < KTOP; ii += 256) {
                const int ixj = ii ^ j;
                if (ixj > ii) {
                    const unsigned long long a = keys[ii], c = keys[ixj];
                    const bool up = ((ii & k) == 0);
                    if ((a > c) == up) { keys[ii] = c; keys[ixj] = a; }
                }
            }
            __syncthreads();
        }
    }
    if (t < KNN)
        out_knn[(size_t)blockIdx.x * KNN + t] = (float)(unsigned)(keys[t] & 0xffffffffu);
}

// ---------------------------------------------------------------------------
extern "C" void kernel_launch(void* const* d_in, const int* in_sizes, int n_in,
                              void* d_out, int out_size, void* d_ws, size_t ws_size,
                              hipStream_t stream)
{
    const float* x     = (const float*)d_in[0];
    const float* xorig = (const float*)d_in[1];
    const float* xyz   = (const float*)d_in[2];
    const int*   esrc  = (const int*)d_in[3];
    // d_in[4] = edge_dst: dst(e) == e / KG by construction, unused
    const float* thw = (const float*)d_in[5];
    const float* thb = (const float*)d_in[6];
    const float* phw = (const float*)d_in[7];
    const float* phb = (const float*)d_in[8];
    const float* w1  = (const float*)d_in[9];
    const float* b1  = (const float*)d_in[10];
    const float* g1  = (const float*)d_in[11];
    const float* be1 = (const float*)d_in[12];
    const float* m1  = (const float*)d_in[13];
    const float* v1  = (const float*)d_in[14];
    const float* w2  = (const float*)d_in[15];
    const float* b2  = (const float*)d_in[16];
    const float* g2  = (const float*)d_in[17];
    const float* be2 = (const float*)d_in[18];
    const float* m2  = (const float*)d_in[19];
    const float* v2  = (const float*)d_in[20];
    const float* w3  = (const float*)d_in[21];
    const float* b3  = (const float*)d_in[22];

    float* ws   = (float*)d_ws;
    float* T    = ws;                          // N*C
    float* x1   = ws + (size_t)N * C;          // N*C  (holds R, overwritten to x1)
    float* t1   = ws + 2 * (size_t)N * C;      // N*64
    float* sc   = t1 + (size_t)N * 64;         // N
    int*   perm = (int*)(sc + N);              // B*KTOP
    float* xsel = (float*)(perm + B * KTOP);   // B*KTOP*3

    float* out     = (float*)d_out;
    float* o_knn   = out;                                  // B*KTOP*KNN
    float* o_xnew  = o_knn + (size_t)B * KTOP * KNN;       // B*KTOP*C
    float* o_xcopy = o_xnew + (size_t)B * KTOP * C;        // B*KTOP*C
    float* o_score = o_xcopy + (size_t)B * KTOP * C;       // B*N_PER
    float* o_topk  = o_score + (size_t)B * N_PER;          // B*KTOP

    k1_dual_gemm<<<dim3(N / 64, C / 64), 256, 0, stream>>>(x, thw, phw, thb, phb, T, x1);
    k2a_gather_max<<<N, 256, 0, stream>>>(esrc, T, x1);
    k2b_layer1<<<dim3(N / 64, 1), 256, 0, stream>>>(x1, w1, b1, g1, be1, m1, v1, t1);
    k2c_score<<<N / 8, 256, 0, stream>>>(t1, w2, b2, g2, be2, m2, v2, w3, b3, sc, o_score);
    k3_topk<<<B, 256, 0, stream>>>(sc, o_topk, perm);
    k4_gather<<<B * KTOP, 256, 0, stream>>>(perm, x1, xorig, xyz, o_xnew, o_xcopy, xsel);
    k5_knn<<<B * KTOP, 256, 0, stream>>>(xsel, o_knn);
}

// Round 2
// 276.487 us; speedup vs baseline: 1.1892x; 1.1892x over previous
//
#include <hip/hip_runtime.h>
#include <math.h>

// Problem constants (fixed by the reference)
constexpr int B     = 8;
constexpr int N_PER = 2048;
constexpr int C     = 256;
constexpr int KG    = 16;
constexpr int KTOP  = 512;
constexpr int KNN   = 32;
constexpr int N     = B * N_PER;   // 16384
constexpr float EPS = 1e-5f;

// ---------------------------------------------------------------------------
// K1: T = x @ theta_w.T ;  R = x + x @ phi_w.T + (theta_b + phi_b) - T
// 64x64 output tile per block, BK=16, fp32 VALU outer-product GEMM.
// grid (N/64, C/64), block 256.
// ---------------------------------------------------------------------------
__global__ __launch_bounds__(256) void k1_dual_gemm(
    const float* __restrict__ x, const float* __restrict__ thw,
    const float* __restrict__ phw, const float* __restrict__ thb,
    const float* __restrict__ phb, float* __restrict__ T, float* __restrict__ R)
{
    constexpr int BK = 16, ST = 68;
    __shared__ float Xs[BK * ST];
    __shared__ float Wt[BK * ST];
    __shared__ float Wp[BK * ST];
    const int tid  = threadIdx.x;
    const int row0 = blockIdx.x * 64;
    const int n0   = blockIdx.y * 64;
    const int tx = tid & 15, ty = tid >> 4;
    const int lm = tid >> 2, lq = (tid & 3) << 2;

    float aT[4][4] = {{0.f}}, aQ[4][4] = {{0.f}};

    for (int k0 = 0; k0 < C; k0 += BK) {
        float4 fx = *(const float4*)(x   + (size_t)(row0 + lm) * C + k0 + lq);
        float4 ft = *(const float4*)(thw + (size_t)(n0   + lm) * C + k0 + lq);
        float4 fp = *(const float4*)(phw + (size_t)(n0   + lm) * C + k0 + lq);
        __syncthreads();
        Xs[(lq + 0) * ST + lm] = fx.x;  Xs[(lq + 1) * ST + lm] = fx.y;
        Xs[(lq + 2) * ST + lm] = fx.z;  Xs[(lq + 3) * ST + lm] = fx.w;
        Wt[(lq + 0) * ST + lm] = ft.x;  Wt[(lq + 1) * ST + lm] = ft.y;
        Wt[(lq + 2) * ST + lm] = ft.z;  Wt[(lq + 3) * ST + lm] = ft.w;
        Wp[(lq + 0) * ST + lm] = fp.x;  Wp[(lq + 1) * ST + lm] = fp.y;
        Wp[(lq + 2) * ST + lm] = fp.z;  Wp[(lq + 3) * ST + lm] = fp.w;
        __syncthreads();
#pragma unroll
        for (int k = 0; k < BK; ++k) {
            float4 a4 = *(const float4*)&Xs[k * ST + (ty << 2)];
            float4 t4 = *(const float4*)&Wt[k * ST + (tx << 2)];
            float4 p4 = *(const float4*)&Wp[k * ST + (tx << 2)];
            float av[4] = {a4.x, a4.y, a4.z, a4.w};
            float tv[4] = {t4.x, t4.y, t4.z, t4.w};
            float pv[4] = {p4.x, p4.y, p4.z, p4.w};
#pragma unroll
            for (int i2 = 0; i2 < 4; ++i2)
#pragma unroll
                for (int j2 = 0; j2 < 4; ++j2) {
                    aT[i2][j2] += av[i2] * tv[j2];
                    aQ[i2][j2] += av[i2] * pv[j2];
                }
        }
    }
#pragma unroll
    for (int i2 = 0; i2 < 4; ++i2) {
        const int gm = row0 + (ty << 2) + i2;
#pragma unroll
        for (int j2 = 0; j2 < 4; ++j2) {
            const int gn = n0 + (tx << 2) + j2;
            const size_t off = (size_t)gm * C + gn;
            const float tval = aT[i2][j2];
            T[off] = tval;
            R[off] = x[off] + aQ[i2][j2] + thb[gn] + phb[gn] - tval;
        }
    }
}

// ---------------------------------------------------------------------------
// K2a: x1[i] = max_{k<16} T[src[i*16+k]] + R[i]   (R overwritten in place)
// ---------------------------------------------------------------------------
__global__ __launch_bounds__(256) void k2a_gather_max(
    const int* __restrict__ esrc, const float* __restrict__ T, float* x1r)
{
    const int i = blockIdx.x;
    const int c = threadIdx.x;
    __shared__ int s[KG];
    if (c < KG) s[c] = esrc[i * KG + c];
    __syncthreads();
    float m = -INFINITY;
#pragma unroll
    for (int k = 0; k < KG; ++k) m = fmaxf(m, T[(size_t)s[k] * C + c]);
    const size_t off = (size_t)i * C + c;
    x1r[off] = m + x1r[off];
}

// ---------------------------------------------------------------------------
// K2b: t1 = BN1(ReLU(x1 @ w1.T + b1))   [N x 64]
// ---------------------------------------------------------------------------
__global__ __launch_bounds__(256) void k2b_layer1(
    const float* __restrict__ x1, const float* __restrict__ w1,
    const float* __restrict__ b1, const float* __restrict__ g1,
    const float* __restrict__ be1, const float* __restrict__ m1,
    const float* __restrict__ v1, float* __restrict__ t1)
{
    constexpr int BK = 16, ST = 68;
    __shared__ float Xs[BK * ST];
    __shared__ float Ws[BK * ST];
    const int tid  = threadIdx.x;
    const int row0 = blockIdx.x * 64;
    const int tx = tid & 15, ty = tid >> 4;
    const int lm = tid >> 2, lq = (tid & 3) << 2;

    float acc[4][4] = {{0.f}};
    for (int k0 = 0; k0 < C; k0 += BK) {
        float4 fx = *(const float4*)(x1 + (size_t)(row0 + lm) * C + k0 + lq);
        float4 fw = *(const float4*)(w1 + (size_t)lm * C + k0 + lq);
        __syncthreads();
        Xs[(lq + 0) * ST + lm] = fx.x;  Xs[(lq + 1) * ST + lm] = fx.y;
        Xs[(lq + 2) * ST + lm] = fx.z;  Xs[(lq + 3) * ST + lm] = fx.w;
        Ws[(lq + 0) * ST + lm] = fw.x;  Ws[(lq + 1) * ST + lm] = fw.y;
        Ws[(lq + 2) * ST + lm] = fw.z;  Ws[(lq + 3) * ST + lm] = fw.w;
        __syncthreads();
#pragma unroll
        for (int k = 0; k < BK; ++k) {
            float4 a4 = *(const float4*)&Xs[k * ST + (ty << 2)];
            float4 w4 = *(const float4*)&Ws[k * ST + (tx << 2)];
            float av[4] = {a4.x, a4.y, a4.z, a4.w};
            float wv[4] = {w4.x, w4.y, w4.z, w4.w};
#pragma unroll
            for (int i2 = 0; i2 < 4; ++i2)
#pragma unroll
                for (int j2 = 0; j2 < 4; ++j2) acc[i2][j2] += av[i2] * wv[j2];
        }
    }
#pragma unroll
    for (int i2 = 0; i2 < 4; ++i2) {
        const int gm = row0 + (ty << 2) + i2;
#pragma unroll
        for (int j2 = 0; j2 < 4; ++j2) {
            const int gn = (tx << 2) + j2;
            float y = acc[i2][j2] + b1[gn];
            y = fmaxf(y, 0.f);
            const float inv = 1.0f / sqrtf(v1[gn] + EPS);
            y = (y - m1[gn]) * inv * g1[gn] + be1[gn];
            t1[(size_t)gm * 64 + gn] = y;
        }
    }
}

// ---------------------------------------------------------------------------
// K2c: layers 2-3 -> score.  8 nodes per block, block 256.
// ---------------------------------------------------------------------------
__global__ __launch_bounds__(256) void k2c_score(
    const float* __restrict__ t1,
    const float* __restrict__ w2, const float* __restrict__ b2,
    const float* __restrict__ g2, const float* __restrict__ be2,
    const float* __restrict__ m2, const float* __restrict__ v2,
    const float* __restrict__ w3, const float* __restrict__ b3,
    float* __restrict__ score_ws, float* __restrict__ out_score)
{
    __shared__ float w2s[32 * 65];
    __shared__ float t1s[8 * 65];
    __shared__ float zs[8 * 33];
    __shared__ float w3s[32];
    const int t = threadIdx.x;
    const int node0 = blockIdx.x * 8;

    for (int idx = t; idx < 2048; idx += 256) {
        const int oo = idx >> 6, jj = idx & 63;
        w2s[oo * 65 + jj] = w2[idx];
    }
    if (t < 32) w3s[t] = w3[t];
    for (int idx = t; idx < 512; idx += 256) {
        const int nn = idx >> 6, jj = idx & 63;
        t1s[nn * 65 + jj] = t1[(size_t)(node0 + nn) * 64 + jj];
    }
    __syncthreads();

    const int nl = t >> 5, o = t & 31;
    float z = 0.f;
#pragma unroll
    for (int j = 0; j < 64; ++j) z += t1s[nl * 65 + j] * w2s[o * 65 + j];
    z += b2[o];
    z = fmaxf(z, 0.f);
    const float inv = 1.0f / sqrtf(v2[o] + EPS);
    z = (z - m2[o]) * inv * g2[o] + be2[o];
    zs[nl * 33 + o] = z;
    __syncthreads();

    if (t < 8) {
        float s = 0.f;
#pragma unroll
        for (int j = 0; j < 32; ++j) s += zs[t * 33 + j] * w3s[j];
        s += b3[0];
        const int node = node0 + t;
        score_ws[node]  = s;
        out_score[node] = s;
    }
}

// ---------------------------------------------------------------------------
// K3: per-batch top-512 of 2048, descending, ties -> lower index first.
// 1024 threads: one compare-exchange per thread per substep (was 4 serialized
// LDS round-trips with 256 threads -> pure latency, 63 us).
// ---------------------------------------------------------------------------
__global__ __launch_bounds__(1024) void k3_topk(
    const float* __restrict__ score, float* __restrict__ out_topk,
    int* __restrict__ perm)
{
    __shared__ unsigned long long keys[N_PER];
    const int b = blockIdx.x;
    const int t = threadIdx.x;
    for (int i = t; i < N_PER; i += 1024) {
        const float v = score[b * N_PER + i];
        unsigned u = __float_as_uint(v);
        const unsigned ua = (u & 0x80000000u) ? ~u : (u | 0x80000000u);
        const unsigned ud = ~ua;   // descending-monotone
        keys[i] = ((unsigned long long)ud << 32) | (unsigned)i;
    }
    __syncthreads();
    for (int k = 2; k <= N_PER; k <<= 1) {
        for (int j = k >> 1; j > 0; j >>= 1) {
            for (int i = t; i < N_PER; i += 1024) {
                const int ixj = i ^ j;
                if (ixj > i) {
                    const unsigned long long a = keys[i], c = keys[ixj];
                    const bool up = ((i & k) == 0);
                    if ((a > c) == up) { keys[i] = c; keys[ixj] = a; }
                }
            }
            __syncthreads();
        }
    }
    for (int r = t; r < KTOP; r += 1024) {
        const int idx = (int)(keys[r] & 0xffffffffu);
        out_topk[b * KTOP + r] = score[b * N_PER + idx];
        perm[b * KTOP + r] = b * N_PER + idx;
    }
}

// ---------------------------------------------------------------------------
// K4: gather x_new = x1[perm], x_copy = x_origin[perm], xyz_sel = xyz[perm].
// ---------------------------------------------------------------------------
__global__ __launch_bounds__(256) void k4_gather(
    const int* __restrict__ perm, const float* __restrict__ x1,
    const float* __restrict__ xorig, const float* __restrict__ xyz,
    float* __restrict__ out_xnew, float* __restrict__ out_xcopy,
    float* __restrict__ xyz_sel)
{
    const int row = blockIdx.x;
    const int t = threadIdx.x;
    const int g = perm[row];
    out_xnew [(size_t)row * C + t] = x1   [(size_t)g * C + t];
    out_xcopy[(size_t)row * C + t] = xorig[(size_t)g * C + t];
    if (t < 3) xyz_sel[row * 3 + t] = xyz[g * 3 + t];
}

// ---------------------------------------------------------------------------
// K5: 32-NN among 512 selected points, 4 query points per block.
// Partial selection: sort 16 chunks of 32 asc (15 substeps), then 4 rounds of
// bitonic top-32 merge (min(a[i],b[31-i]) + 5-substep clean). Keys packed
// (d2_bits<<32)|idx -> exact lax.top_k tie-break (lower idx first).
// grid B*KTOP/4 = 1024, block 256.
// ---------------------------------------------------------------------------
__global__ __launch_bounds__(256) void k5_knn(
    const float* __restrict__ xyz_sel, float* __restrict__ out_knn)
{
    constexpr int G = 4;                 // query points per block
    __shared__ float px[KTOP], py[KTOP], pz[KTOP];
    __shared__ unsigned long long keys[G * KTOP];
    const int t    = threadIdx.x;
    const int q0   = blockIdx.x * G;         // global query row
    const int b    = q0 >> 9;                // batch
    const int i0   = q0 & 511;               // local query index base

    for (int idx = t; idx < KTOP; idx += 256) {
        const float* p = xyz_sel + ((size_t)b * KTOP + idx) * 3;
        px[idx] = p[0]; py[idx] = p[1]; pz[idx] = p[2];
    }
    __syncthreads();

    // build keys for the G queries
    for (int w = t; w < G * KTOP; w += 256) {
        const int p = w >> 9, idx = w & 511;
        const float qx = px[i0 + p], qy = py[i0 + p], qz = pz[i0 + p];
        const float dx = __fsub_rn(qx, px[idx]);
        const float dy = __fsub_rn(qy, py[idx]);
        const float dz = __fsub_rn(qz, pz[idx]);
        const float d2 = __fadd_rn(__fadd_rn(__fmul_rn(dx, dx), __fmul_rn(dy, dy)),
                                   __fmul_rn(dz, dz));
        keys[w] = ((unsigned long long)__float_as_uint(d2) << 32) | (unsigned)idx;
    }
    __syncthreads();

    // phase 1: sort each 32-chunk ascending (independent, all G arrays at once)
    for (int k = 2; k <= 32; k <<= 1) {
        for (int j = k >> 1; j > 0; j >>= 1) {
            for (int i = t; i < G * KTOP; i += 256) {
                const int ixj = i ^ j;
                if (ixj > i) {
                    const int il = i & 31;
                    const unsigned long long a = keys[i], c = keys[ixj];
                    const bool up = ((il & k) == 0) || (k == 32);
                    if ((a > c) == up) { keys[i] = c; keys[ixj] = a; }
                }
            }
            __syncthreads();
        }
    }

    // phase 2: 4 rounds of pairwise top-32 merge
    for (int r = 0; r < 4; ++r) {
        const int npairs = 8 >> r;
        const int total  = G * npairs * 32;
        // merge: a[i] = min(a[i], b[31-i])  (result bitonic, holds smallest 32)
        for (int w = t; w < total; w += 256) {
            const int p  = w / (npairs * 32);
            const int rm = w - p * (npairs * 32);
            const int m  = rm >> 5, i = rm & 31;
            const int baseA = p * KTOP + m * (64 << r);
            const int baseB = baseA + (32 << r);
            const unsigned long long a = keys[baseA + i];
            const unsigned long long c = keys[baseB + 31 - i];
            keys[baseA + i] = (c < a) ? c : a;
        }
        __syncthreads();
        // clean: sort the 32-length bitonic sequence ascending
        for (int j = 16; j > 0; j >>= 1) {
            for (int w = t; w < total; w += 256) {
                const int p  = w / (npairs * 32);
                const int rm = w - p * (npairs * 32);
                const int m  = rm >> 5, i = rm & 31;
                const int ixj = i ^ j;
                if (ixj > i) {
                    const int baseA = p * KTOP + m * (64 << r);
                    const unsigned long long a = keys[baseA + i], c = keys[baseA + ixj];
                    if (a > c) { keys[baseA + i] = c; keys[baseA + ixj] = a; }
                }
            }
            __syncthreads();
        }
    }

    if (t < G * KNN) {
        const int p = t >> 5, r = t & 31;
        out_knn[((size_t)(q0 + p)) * KNN + r] =
            (float)(unsigned)(keys[p * KTOP + r] & 0xffffffffu);
    }
}

// ---------------------------------------------------------------------------
extern "C" void kernel_launch(void* const* d_in, const int* in_sizes, int n_in,
                              void* d_out, int out_size, void* d_ws, size_t ws_size,
                              hipStream_t stream)
{
    const float* x     = (const float*)d_in[0];
    const float* xorig = (const float*)d_in[1];
    const float* xyz   = (const float*)d_in[2];
    const int*   esrc  = (const int*)d_in[3];
    const float* thw = (const float*)d_in[5];
    const float* thb = (const float*)d_in[6];
    const float* phw = (const float*)d_in[7];
    const float* phb = (const float*)d_in[8];
    const float* w1  = (const float*)d_in[9];
    const float* b1  = (const float*)d_in[10];
    const float* g1  = (const float*)d_in[11];
    const float* be1 = (const float*)d_in[12];
    const float* m1  = (const float*)d_in[13];
    const float* v1  = (const float*)d_in[14];
    const float* w2  = (const float*)d_in[15];
    const float* b2  = (const float*)d_in[16];
    const float* g2  = (const float*)d_in[17];
    const float* be2 = (const float*)d_in[18];
    const float* m2  = (const float*)d_in[19];
    const float* v2  = (const float*)d_in[20];
    const float* w3  = (const float*)d_in[21];
    const float* b3  = (const float*)d_in[22];

    float* ws   = (float*)d_ws;
    float* T    = ws;                          // N*C
    float* x1   = ws + (size_t)N * C;          // N*C  (holds R, overwritten to x1)
    float* t1   = ws + 2 * (size_t)N * C;      // N*64
    float* sc   = t1 + (size_t)N * 64;         // N
    int*   perm = (int*)(sc + N);              // B*KTOP
    float* xsel = (float*)(perm + B * KTOP);   // B*KTOP*3

    float* out     = (float*)d_out;
    float* o_knn   = out;                                  // B*KTOP*KNN
    float* o_xnew  = o_knn + (size_t)B * KTOP * KNN;       // B*KTOP*C
    float* o_xcopy = o_xnew + (size_t)B * KTOP * C;        // B*KTOP*C
    float* o_score = o_xcopy + (size_t)B * KTOP * C;       // B*N_PER
    float* o_topk  = o_score + (size_t)B * N_PER;          // B*KTOP

    k1_dual_gemm<<<dim3(N / 64, C / 64), 256, 0, stream>>>(x, thw, phw, thb, phb, T, x1);
    k2a_gather_max<<<N, 256, 0, stream>>>(esrc, T, x1);
    k2b_layer1<<<dim3(N / 64, 1), 256, 0, stream>>>(x1, w1, b1, g1, be1, m1, v1, t1);
    k2c_score<<<N / 8, 256, 0, stream>>>(t1, w2, b2, g2, be2, m2, v2, w3, b3, sc, o_score);
    k3_topk<<<B, 1024, 0, stream>>>(sc, o_topk, perm);
    k4_gather<<<B * KTOP, 256, 0, stream>>>(perm, x1, xorig, xyz, o_xnew, o_xcopy, xsel);
    k5_knn<<<B * KTOP / 4, 256, 0, stream>>>(xsel, o_knn);
}